// Round 14
// baseline (200.124 us; speedup 1.0000x reference)
//
#include <hip/hip_runtime.h>
#include <hip/hip_bf16.h>

// B=16,S=4096,H=512 ; G=2,V=320,D=256 (Dg=128)
constexpr int BT = 65536;
constexpr int K  = 512;
constexpr int V  = 320;
constexpr int G  = 2;
constexpr int Dg = 128;
constexpr int MT = 64;           // rows per block; 5 waves, wave = 64r x 64c (2x2 32-tiles)
constexpr int NSTEP = 16;        // K/32
constexpr size_t WS_IMG = 4096;  // 32x32-frag-ordered B img (640 KB)

using short8  = __attribute__((ext_vector_type(8)))  short;
using f32x16  = __attribute__((ext_vector_type(16))) float;

static __device__ __forceinline__ unsigned short f2bf(float x) {
    unsigned u = __float_as_uint(x);
    unsigned r = 0x7FFFu + ((u >> 16) & 1u);   // RNE
    return (unsigned short)((u + r) >> 16);
}
static __device__ __forceinline__ unsigned pk2(float a, float b) {
    return (unsigned)f2bf(a) | ((unsigned)f2bf(b) << 16);
}
static __device__ __forceinline__ f32x16 mfma32(short8 a, short8 b, f32x16 c) {
    return __builtin_amdgcn_mfma_f32_32x32x16_bf16(a, b, c, 0, 0, 0);
}

// ---- prep: 32x32x16-fragment-ordered bf16 B image ----
// panel p = g*16+t (20 KB each); chunk pos = (s2*10+ct)*64+lane, 16 B:
// bf16 W[t*32 + s2*16 + (lane>>5)*8 + j][g*320 + ct*32 + (lane&31)], j=0..7
__global__ __launch_bounds__(256) void vq_prep(const float* __restrict__ Wm,
                                               unsigned char* __restrict__ img)
{
    int id   = blockIdx.x * 256 + threadIdx.x;   // 0..40959
    int lane = id & 63;
    int q    = id >> 6;
    int s2ct = q % 20;
    int tk   = q / 20;         // g*16+t
    int ct   = s2ct % 10;
    int s2   = s2ct / 10;
    int g    = tk >> 4;
    int t    = tk & 15;
    int col  = g * V + ct * 32 + (lane & 31);
    int kb   = t * 32 + s2 * 16 + (lane >> 5) * 8;
    unsigned p[4];
#pragma unroll
    for (int jj = 0; jj < 4; ++jj)
        p[jj] = pk2(Wm[(size_t)(kb + 2 * jj) * 640 + col],
                    Wm[(size_t)(kb + 2 * jj + 1) * 640 + col]);
    *reinterpret_cast<uint4*>(img + (size_t)id * 16) = make_uint4(p[0], p[1], p[2], p[3]);
}

// ---- main: bf16 32x32x16-MFMA GEMM (64x320x512) + argmax + gather + hist ----
// grid 2048: g=(bid>>3)&1, rblk=(bid&7)|((bid>>4)<<3) (bid,bid+8 same XCD share hs).
// LDS 24KB: A frag-ordered [0,4K): region (rt*2+s2)*1024, slot lane*16;
//           B [4K,24K): (s2*10+ct)*1024 + lane*16.
__global__ __launch_bounds__(320) void vq_main(
    const float* __restrict__ hs, const unsigned char* __restrict__ img,
    const float* __restrict__ bv, const float* __restrict__ cbv,
    float* __restrict__ out, unsigned int* __restrict__ hist)
{
    __shared__ __align__(16) unsigned char smem[24576];

    const int tid  = threadIdx.x;
    const int bid  = blockIdx.x;
    const int g    = (bid >> 3) & 1;
    const int rblk = (bid & 7) | ((bid >> 4) << 3);
    const int r0   = rblk * MT;
    const int w    = tid >> 6;      // wave 0..4: cols w*64 .. w*64+63
    const int lane = tid & 63;
    const int l5   = lane & 31;
    const int hi   = lane >> 5;

    f32x16 acc[2][2] = {};          // [rt][cti] 32x32 tiles

    // A staging: thread t<256: r = t>>2, c8 = t&3 (8 floats of k); writes frag slot
    const int arow = tid >> 2, ac8 = tid & 3;
    const float* aptr = hs + (size_t)(r0 + arow) * K + ac8 * 8;
    const int awoff = ((arow >> 5) * 2 + (ac8 >> 1)) * 1024 + ((arow & 31) + 32 * (ac8 & 1)) * 16;
    // B source: linear copy of panel (20KB) per step
    const unsigned char* bsrc = img + (size_t)g * 327680 + (size_t)tid * 16;

    auto packA = [&](float4 x, float4 y) {
        if (tid < 256)
            *reinterpret_cast<uint4*>(&smem[awoff]) =
                make_uint4(pk2(x.x, x.y), pk2(x.z, x.w), pk2(y.x, y.y), pk2(y.z, y.w));
    };

    // prologue: A(0) in flight
    float4 ax = make_float4(0,0,0,0), ay = ax;
    if (tid < 256) { ax = *reinterpret_cast<const float4*>(aptr);
                     ay = *reinterpret_cast<const float4*>(aptr + 4); }

    for (int t = 0; t < NSTEP; ++t) {
        // ---- stage: B panel (20KB) via LDS-DMA (4 x 5KB), A convert+write ----
        const unsigned char* bs = bsrc + (size_t)t * 20480;
#pragma unroll
        for (int i = 0; i < 4; ++i)
            __builtin_amdgcn_global_load_lds(
                (const __attribute__((address_space(1))) void*)(bs + i * 5120),
                (__attribute__((address_space(3))) void*)(&smem[4096 + i * 5120 + tid * 16]),
                16, 0, 0);
        packA(ax, ay);
        __syncthreads();
        // ---- compute; A(t+1) issued first (drained at barrier 2, hidden under MFMA) ----
        if (t + 1 < NSTEP && tid < 256) {
            ax = *reinterpret_cast<const float4*>(aptr + (t + 1) * 32);
            ay = *reinterpret_cast<const float4*>(aptr + (t + 1) * 32 + 4);
        }
#pragma unroll
        for (int s2 = 0; s2 < 2; ++s2) {
            short8 av0 = *reinterpret_cast<const short8*>(&smem[(0 * 2 + s2) * 1024 + lane * 16]);
            short8 av1 = *reinterpret_cast<const short8*>(&smem[(1 * 2 + s2) * 1024 + lane * 16]);
            short8 bv0 = *reinterpret_cast<const short8*>(&smem[4096 + (s2 * 10 + 2 * w)     * 1024 + lane * 16]);
            short8 bv1 = *reinterpret_cast<const short8*>(&smem[4096 + (s2 * 10 + 2 * w + 1) * 1024 + lane * 16]);
            acc[0][0] = mfma32(av0, bv0, acc[0][0]);
            acc[0][1] = mfma32(av0, bv1, acc[0][1]);
            acc[1][0] = mfma32(av1, bv0, acc[1][0]);
            acc[1][1] = mfma32(av1, bv1, acc[1][1]);
        }
        __syncthreads();
    }

    // ---- epilogue: bias + argmax ----
    // C layout (m74/m101): col = lane&31, row = (reg&3) + 8*(reg>>2) + 4*(lane>>5)
    float bias0 = bv[g * V + w * 64 + l5];
    float bias1 = bv[g * V + w * 64 + 32 + l5];

    float* red_v = reinterpret_cast<float*>(smem);          // [64][5]
    int*   red_i = reinterpret_cast<int*>(smem + 2048);     // [64][5]
    int*   idx_s = reinterpret_cast<int*>(smem + 4096);     // [64]

#pragma unroll
    for (int rt = 0; rt < 2; ++rt) {
#pragma unroll
        for (int reg = 0; reg < 16; ++reg) {
            float v0 = acc[rt][0][reg] + bias0;
            float v1 = acc[rt][1][reg] + bias1;
            float bestv = v0;
            int   besti = w * 64 + l5;
            if (v1 > bestv) { bestv = v1; besti = w * 64 + 32 + l5; }
#pragma unroll
            for (int m = 1; m < 32; m <<= 1) {   // butterfly within each 32-lane half
                float ov = __shfl_xor(bestv, m);
                int   oi = __shfl_xor(besti, m);
                if (ov > bestv || (ov == bestv && oi < besti)) { bestv = ov; besti = oi; }
            }
            if (l5 == 0) {
                int row = rt * 32 + (reg & 3) + 8 * (reg >> 2) + 4 * hi;
                red_v[row * 5 + w] = bestv;
                red_i[row * 5 + w] = besti;
            }
        }
    }
    __syncthreads();

    int my_bi = -1;
    if (tid < MT) {
        float bb = red_v[tid * 5]; int bi = red_i[tid * 5];
#pragma unroll
        for (int c = 1; c < 5; ++c) {
            float v = red_v[tid * 5 + c]; int ii = red_i[tid * 5 + c];
            if (v > bb || (v == bb && ii < bi)) { bb = v; bi = ii; }
        }
        idx_s[tid] = bi;
        my_bi = bi;
    }
    __syncthreads();

    // ---- gather: 64 rows x 32 float4 = 2048 chunks, <=7 per thread ----
#pragma unroll
    for (int i = 0; i < 7; ++i) {
        int idx = i * 320 + tid;
        if (idx < 2048) {
            int row = idx >> 5;
            int d4  = idx & 31;
            int vi  = idx_s[row];
            float4 val = *reinterpret_cast<const float4*>(&cbv[((size_t)(g * V + vi)) * Dg + d4 * 4]);
            *reinterpret_cast<float4*>(&out[((size_t)(r0 + row)) * (G * Dg) + g * Dg + d4 * 4]) = val;
        }
    }
    // hist atomic LAST: no barrier after -> its latency never drains mid-kernel
    if (my_bi >= 0) atomicAdd(&hist[g * V + my_bi], 1u);
}

// Perplexity from histogram: one wave.
__global__ void vq_ppl(const unsigned int* __restrict__ hist, float* __restrict__ outp)
{
    int lane = threadIdx.x;  // 64
    float ppl = 0.0f;
    for (int g = 0; g < G; ++g) {
        float local = 0.0f;
        for (int v = lane; v < V; v += 64) {
            float m = (float)hist[g * V + v] * (1.0f / (float)BT);
            local += m * logf(m + 1e-7f);
        }
#pragma unroll
        for (int off = 32; off; off >>= 1) local += __shfl_down(local, off);
        if (lane == 0) ppl += expf(-local);
    }
    if (lane == 0) outp[0] = ppl;
}

extern "C" void kernel_launch(void* const* d_in, const int* in_sizes, int n_in,
                              void* d_out, int out_size, void* d_ws, size_t ws_size,
                              hipStream_t stream)
{
    const float* hs  = (const float*)d_in[0];   // (65536, 512)
    const float* Wm  = (const float*)d_in[1];   // (512, 640)
    const float* bv  = (const float*)d_in[2];   // (640,)
    const float* cbv = (const float*)d_in[3];   // (640, 128)
    float* out = (float*)d_out;                 // 65536*256 floats + 1 float perplexity

    unsigned int*  hist = (unsigned int*)d_ws;
    unsigned char* img  = (unsigned char*)d_ws + WS_IMG;

    hipMemsetAsync(d_ws, 0, G * V * sizeof(unsigned int), stream);
    vq_prep<<<160, 256, 0, stream>>>(Wm, img);
    vq_main<<<2048, 320, 0, stream>>>(hs, img, bv, cbv, out, hist);
    vq_ppl<<<1, 64, 0, stream>>>(hist, out + (size_t)BT * G * Dg);
}

// Round 15
// 131.467 us; speedup vs baseline: 1.5222x; 1.5222x over previous
//
#include <hip/hip_runtime.h>
#include <hip/hip_bf16.h>

// B=16,S=4096,H=512 ; G=2,V=320,D=256 (Dg=128)
constexpr int BT = 65536;
constexpr int K  = 512;
constexpr int V  = 320;
constexpr int G  = 2;
constexpr int Dg = 128;
constexpr int MT = 64;           // rows per block; 4 waves = 4 col-quarters
constexpr int NSTEP = 16;        // K/32
constexpr size_t WS_IMG = 4096;  // frag-ordered B img (640 KB)

using short8 = __attribute__((ext_vector_type(8))) short;
using f32x4  = __attribute__((ext_vector_type(4))) float;

static __device__ __forceinline__ unsigned short f2bf(float x) {
    unsigned u = __float_as_uint(x);
    unsigned r = 0x7FFFu + ((u >> 16) & 1u);   // RNE
    return (unsigned short)((u + r) >> 16);
}
static __device__ __forceinline__ unsigned pk2(float a, float b) {
    return (unsigned)f2bf(a) | ((unsigned)f2bf(b) << 16);
}
static __device__ __forceinline__ f32x4 mfma16(short8 a, short8 b, f32x4 c) {
    return __builtin_amdgcn_mfma_f32_16x16x32_bf16(a, b, c, 0, 0, 0);
}
#define SB0() __builtin_amdgcn_sched_barrier(0)

// ---- prep: fragment-ordered bf16 B image (R6 layout, unchanged) ----
// chunk index = (((g*16+t)*4+wc)*5+nt)*64+lane, 16 B each =
// bf16 of W[t*32+(lane>>4)*8 .. +7][g*320 + wc*80+nt*16+(lane&15)]
__global__ __launch_bounds__(256) void vq_prep(const float* __restrict__ Wm,
                                               unsigned char* __restrict__ img)
{
    int id   = blockIdx.x * 256 + threadIdx.x;   // 0..40959
    int lane = id & 63;
    int s    = id >> 6;
    int nt   = s % 5;
    int wcq  = (s / 5) & 3;
    int tk   = s / 20;         // g*16+t
    int g    = tk >> 4;
    int t    = tk & 15;
    int col  = g * V + wcq * 80 + nt * 16 + (lane & 15);
    int kb   = t * 32 + (lane >> 4) * 8;
    unsigned p[4];
#pragma unroll
    for (int jj = 0; jj < 4; ++jj)
        p[jj] = pk2(Wm[(size_t)(kb + 2 * jj) * 640 + col],
                    Wm[(size_t)(kb + 2 * jj + 1) * 640 + col]);
    *reinterpret_cast<uint4*>(img + (size_t)id * 16) = make_uint4(p[0], p[1], p[2], p[3]);
}

// ---- main: bf16 MFMA GEMM (64x320x512), T3/T4 counted-vmcnt pipeline ----
// Key invariant: each wave DMAs and reads ONLY its own B quarter -> vmcnt is
// wave-local, per-step barrier is lgkm-only, B loads span barriers (never drained).
// Per step: [ds_read A,B; lgkm0; MFMA] [issue batch t+2: 5 B-gll + 2 A-glob]
// [vmcnt(7) -> batch t+1 landed] [packA(t+1)] [lgkm0; s_barrier].
// LDS 48KB: A dbuf 2x4KB @0 ; B dbuf 2x20KB @8192.
// grid 2048: g=(bid>>3)&1, rblk=(bid&7)|((bid>>4)<<3) (bid,bid+8 same XCD share hs).
__global__ __launch_bounds__(256) void vq_main(
    const float* __restrict__ hs, const unsigned char* __restrict__ img,
    const float* __restrict__ bv, const float* __restrict__ cbv,
    float* __restrict__ out, unsigned int* __restrict__ hist)
{
    __shared__ __align__(16) unsigned char smem[49152];

    const int tid  = threadIdx.x;
    const int bid  = blockIdx.x;
    const int g    = (bid >> 3) & 1;
    const int rblk = (bid & 7) | ((bid >> 4) << 3);
    const int r0   = rblk * MT;
    const int wc   = tid >> 6;      // wave = col quarter (80 cols)
    const int lane = tid & 63;
    const int l4   = lane & 15;
    const int lc   = lane >> 4;

    f32x4 acc[4][5] = {};

    // A addressing (R10-proven conflict-free swizzle pair)
    const int arow = tid >> 2, akq = tid & 3;
    const float* aptr = hs + (size_t)(r0 + arow) * K + akq * 8;
    const int awoff  = (arow * 64 + akq * 16) ^ (((arow >> 1) & 3) << 4);  // + Abuf sel*4096
    const int a_base = (l4 * 64 + lc * 16) ^ (((l4 >> 1) & 3) << 4);       // + mt*1024
    // B: wave-private quarter, frag-ordered
    const unsigned char* bsrc = img + (size_t)g * 327680 + wc * 5120 + (size_t)lane * 16;
    const int b_lds = 8192 + wc * 5120;   // + (t&1)*20480 + nt*1024 (+lane*16 on read)

    auto issueBatch = [&](int t) {   // 5 B-gll into Bbuf[t&1] + 2 A-globals -> regs
        const unsigned char* s = bsrc + (size_t)t * 20480;
        const int bb = b_lds + (t & 1) * 20480;
#pragma unroll
        for (int i = 0; i < 5; ++i)
            __builtin_amdgcn_global_load_lds(
                (const __attribute__((address_space(1))) void*)(s + i * 1024),
                (__attribute__((address_space(3))) void*)(&smem[bb + i * 1024]), 16, 0, 0);
        float4 x = *reinterpret_cast<const float4*>(aptr + t * 32);
        float4 y = *reinterpret_cast<const float4*>(aptr + t * 32 + 4);
        return make_float4(x.x, x.y, x.z, x.w), x;  // (unused trick removed below)
    };
    (void)issueBatch;  // not used; explicit inline below for exact ordering

    auto packA = [&](float4 x, float4 y, int sel) {
        *reinterpret_cast<uint4*>(&smem[sel * 4096 + awoff]) =
            make_uint4(pk2(x.x, x.y), pk2(x.z, x.w), pk2(y.x, y.y), pk2(y.z, y.w));
    };

    float4 aXa, aYa, aXb, aYb;   // A-regs for batches: a = even t, b = odd t

    // ---- prologue: issue batch0, batch1; vmcnt(7) -> batch0 done; pack A(0) ----
    {
        const unsigned char* s0 = bsrc;
        const int bb0 = b_lds;
#pragma unroll
        for (int i = 0; i < 5; ++i)
            __builtin_amdgcn_global_load_lds(
                (const __attribute__((address_space(1))) void*)(s0 + i * 1024),
                (__attribute__((address_space(3))) void*)(&smem[bb0 + i * 1024]), 16, 0, 0);
        aXa = *reinterpret_cast<const float4*>(aptr);
        aYa = *reinterpret_cast<const float4*>(aptr + 4);
        SB0();
        const unsigned char* s1 = bsrc + 20480;
        const int bb1 = b_lds + 20480;
#pragma unroll
        for (int i = 0; i < 5; ++i)
            __builtin_amdgcn_global_load_lds(
                (const __attribute__((address_space(1))) void*)(s1 + i * 1024),
                (__attribute__((address_space(3))) void*)(&smem[bb1 + i * 1024]), 16, 0, 0);
        aXb = *reinterpret_cast<const float4*>(aptr + 32);
        aYb = *reinterpret_cast<const float4*>(aptr + 36);
        SB0();
        asm volatile("s_waitcnt vmcnt(7)" ::: "memory");   // batch0 complete
        SB0();
        packA(aXa, aYa, 0);
        asm volatile("s_waitcnt lgkmcnt(0)" ::: "memory");
        SB0();
        __builtin_amdgcn_s_barrier();
    }

#pragma unroll
    for (int t = 0; t < NSTEP; ++t) {
        const int cs = t & 1;
        // ---- compute tile t ----
        short8 av[4];
#pragma unroll
        for (int mt = 0; mt < 4; ++mt)
            av[mt] = *reinterpret_cast<const short8*>(&smem[cs * 4096 + a_base + mt * 1024]);
        short8 bvv[5];
#pragma unroll
        for (int nt = 0; nt < 5; ++nt)
            bvv[nt] = *reinterpret_cast<const short8*>(
                &smem[b_lds + cs * 20480 + nt * 1024 + lane * 16]);
        asm volatile("s_waitcnt lgkmcnt(0)" ::: "memory");
        SB0();                                   // rule #18: fence before MFMA
#pragma unroll
        for (int nt = 0; nt < 5; ++nt)
#pragma unroll
            for (int mt = 0; mt < 4; ++mt)
                acc[mt][nt] = mfma16(av[mt], bvv[nt], acc[mt][nt]);
        SB0();                                   // keep gll below MFMA/ds_reads
        // ---- issue batch t+2 (B into Bbuf[t&1] — my reads above are retired) ----
        if (t + 2 < NSTEP) {
            const unsigned char* s = bsrc + (size_t)(t + 2) * 20480;
            const int bb = b_lds + cs * 20480;
#pragma unroll
            for (int i = 0; i < 5; ++i)
                __builtin_amdgcn_global_load_lds(
                    (const __attribute__((address_space(1))) void*)(s + i * 1024),
                    (__attribute__((address_space(3))) void*)(&smem[bb + i * 1024]), 16, 0, 0);
            if (cs) { aXb = *reinterpret_cast<const float4*>(aptr + (t + 2) * 32);
                      aYb = *reinterpret_cast<const float4*>(aptr + (t + 2) * 32 + 4); }
            else    { aXa = *reinterpret_cast<const float4*>(aptr + (t + 2) * 32);
                      aYa = *reinterpret_cast<const float4*>(aptr + (t + 2) * 32 + 4); }
        }
        SB0();
        // ---- counted wait: batch t+1 landed (leaves batch t+2 in flight) ----
        if (t + 2 < NSTEP) asm volatile("s_waitcnt vmcnt(7)" ::: "memory");
        else               asm volatile("s_waitcnt vmcnt(0)" ::: "memory");
        SB0();
        // ---- pack A(t+1) into Abuf[(t+1)&1] ----
        if (t + 1 < NSTEP) {
            if (cs) packA(aXa, aYa, 0);          // t+1 even -> regs 'a'
            else    packA(aXb, aYb, 1);          // t+1 odd  -> regs 'b'
        }
        asm volatile("s_waitcnt lgkmcnt(0)" ::: "memory");
        SB0();
        __builtin_amdgcn_s_barrier();            // lgkm-only barrier; vmcnt stays counted
    }

    // ---- epilogue: bias + argmax (D: col=l4, row=lc*4+reg within 16x16 tile) ----
    float biasv[5];
#pragma unroll
    for (int nt = 0; nt < 5; ++nt) biasv[nt] = bv[g * V + wc * 80 + nt * 16 + l4];

    float* red_v = reinterpret_cast<float*>(smem);          // [64][4]
    int*   red_i = reinterpret_cast<int*>(smem + 1024);     // [64][4]
    int*   idx_s = reinterpret_cast<int*>(smem + 2048);     // [64]

#pragma unroll
    for (int mt = 0; mt < 4; ++mt) {
#pragma unroll
        for (int reg = 0; reg < 4; ++reg) {
            float bestv = acc[mt][0][reg] + biasv[0];
            int   besti = wc * 80 + l4;
#pragma unroll
            for (int nt = 1; nt < 5; ++nt) {
                float v = acc[mt][nt][reg] + biasv[nt];
                int   ci = wc * 80 + nt * 16 + l4;
                if (v > bestv) { bestv = v; besti = ci; }
            }
#pragma unroll
            for (int m = 1; m < 16; m <<= 1) {
                float ov = __shfl_xor(bestv, m);
                int   oi = __shfl_xor(besti, m);
                if (ov > bestv || (ov == bestv && oi < besti)) { bestv = ov; besti = oi; }
            }
            if (l4 == 0) {
                int row = mt * 16 + lc * 4 + reg;
                red_v[row * 4 + wc] = bestv;
                red_i[row * 4 + wc] = besti;
            }
        }
    }
    __syncthreads();

    int my_bi = -1;
    if (tid < MT) {
        float bb = red_v[tid * 4]; int bi = red_i[tid * 4];
#pragma unroll
        for (int c = 1; c < 4; ++c) {
            float v = red_v[tid * 4 + c]; int ii = red_i[tid * 4 + c];
            if (v > bb || (v == bb && ii < bi)) { bb = v; bi = ii; }
        }
        idx_s[tid] = bi;
        my_bi = bi;
    }
    __syncthreads();

    // ---- gather: 64 rows x 32 float4, 8 per thread ----
#pragma unroll
    for (int i = 0; i < 8; ++i) {
        int idx = i * 256 + tid;
        int row = idx >> 5;
        int d4  = idx & 31;
        int vi  = idx_s[row];
        float4 val = *reinterpret_cast<const float4*>(&cbv[((size_t)(g * V + vi)) * Dg + d4 * 4]);
        *reinterpret_cast<float4*>(&out[((size_t)(r0 + row)) * (G * Dg) + g * Dg + d4 * 4]) = val;
    }
    if (my_bi >= 0) atomicAdd(&hist[g * V + my_bi], 1u);   // last: no drain after
}

// Perplexity from histogram: one wave.
__global__ void vq_ppl(const unsigned int* __restrict__ hist, float* __restrict__ outp)
{
    int lane = threadIdx.x;  // 64
    float ppl = 0.0f;
    for (int g = 0; g < G; ++g) {
        float local = 0.0f;
        for (int v = lane; v < V; v += 64) {
            float m = (float)hist[g * V + v] * (1.0f / (float)BT);
            local += m * logf(m + 1e-7f);
        }
#pragma unroll
        for (int off = 32; off; off >>= 1) local += __shfl_down(local, off);
        if (lane == 0) ppl += expf(-local);
    }
    if (lane == 0) outp[0] = ppl;
}

extern "C" void kernel_launch(void* const* d_in, const int* in_sizes, int n_in,
                              void* d_out, int out_size, void* d_ws, size_t ws_size,
                              hipStream_t stream)
{
    const float* hs  = (const float*)d_in[0];   // (65536, 512)
    const float* Wm  = (const float*)d_in[1];   // (512, 640)
    const float* bv  = (const float*)d_in[2];   // (640,)
    const float* cbv = (const float*)d_in[3];   // (640, 128)
    float* out = (float*)d_out;                 // 65536*256 floats + 1 float perplexity

    unsigned int*  hist = (unsigned int*)d_ws;
    unsigned char* img  = (unsigned char*)d_ws + WS_IMG;

    hipMemsetAsync(d_ws, 0, G * V * sizeof(unsigned int), stream);
    vq_prep<<<160, 256, 0, stream>>>(Wm, img);
    vq_main<<<2048, 256, 0, stream>>>(hs, img, bv, cbv, out, hist);
    vq_ppl<<<1, 64, 0, stream>>>(hist, out + (size_t)BT * G * Dg);
}

// Round 16
// 99.722 us; speedup vs baseline: 2.0068x; 1.3183x over previous
//
#include <hip/hip_runtime.h>
#include <hip/hip_bf16.h>

// B=16,S=4096,H=512 ; G=2,V=320,D=256 (Dg=128)
constexpr int BT = 65536;
constexpr int K  = 512;
constexpr int V  = 320;
constexpr int G  = 2;
constexpr int Dg = 128;
constexpr int MT = 64;           // rows per block; 8 waves = 2 row-halves x 4 col-quarters
constexpr int NSTEP = 8;         // K/64 (BK=64 — R12, session best)
constexpr size_t WS_IMG = 4096;  // frag-ordered B img (640 KB)

using short8 = __attribute__((ext_vector_type(8))) short;
using f32x4  = __attribute__((ext_vector_type(4))) float;

static __device__ __forceinline__ unsigned short f2bf(float x) {
    unsigned u = __float_as_uint(x);
    unsigned r = 0x7FFFu + ((u >> 16) & 1u);   // RNE
    return (unsigned short)((u + r) >> 16);
}
static __device__ __forceinline__ unsigned pk2(float a, float b) {
    return (unsigned)f2bf(a) | ((unsigned)f2bf(b) << 16);
}
static __device__ __forceinline__ f32x4 mfma16(short8 a, short8 b, f32x4 c) {
    return __builtin_amdgcn_mfma_f32_16x16x32_bf16(a, b, c, 0, 0, 0);
}

// ---- prep: fragment-ordered bf16 B image (unchanged since R6) ----
// chunk index = (((g*16+t)*4+wc)*5+nt)*64+lane, 16 B each =
// bf16 of W[t*32+(lane>>4)*8 .. +7][g*320 + wc*80+nt*16+(lane&15)]
__global__ __launch_bounds__(256) void vq_prep(const float* __restrict__ Wm,
                                               unsigned char* __restrict__ img)
{
    int id   = blockIdx.x * 256 + threadIdx.x;   // 0..40959
    int lane = id & 63;
    int s    = id >> 6;
    int nt   = s % 5;
    int wcq  = (s / 5) & 3;
    int tk   = s / 20;         // g*16+t
    int g    = tk >> 4;
    int t    = tk & 15;
    int col  = g * V + wcq * 80 + nt * 16 + (lane & 15);
    int kb   = t * 32 + (lane >> 4) * 8;
    unsigned p[4];
#pragma unroll
    for (int jj = 0; jj < 4; ++jj)
        p[jj] = pk2(Wm[(size_t)(kb + 2 * jj) * 640 + col],
                    Wm[(size_t)(kb + 2 * jj + 1) * 640 + col]);
    *reinterpret_cast<uint4*>(img + (size_t)id * 16) = make_uint4(p[0], p[1], p[2], p[3]);
}

// ---- main: bf16 MFMA GEMM (64x320x512), BK=64, 8 k-steps, 8 waves (R12) ----
// + T5 setprio around MFMA cluster, + hist atomic last (no post-atomic drain).
// LDS 48KB single-buf: A [0,8K) swizzled [64 rows][64 k] bf16 ; B [8K,48K) two panels.
// grid 2048: g=(bid>>3)&1, rblk=(bid&7)|((bid>>4)<<3) (bid,bid+8 same XCD share hs).
__global__ __launch_bounds__(512) void vq_main(
    const float* __restrict__ hs, const unsigned char* __restrict__ img,
    const float* __restrict__ bv, const float* __restrict__ cbv,
    float* __restrict__ out, unsigned int* __restrict__ hist)
{
    __shared__ __align__(16) unsigned char smem[49152];

    const int tid  = threadIdx.x;
    const int bid  = blockIdx.x;
    const int g    = (bid >> 3) & 1;
    const int rblk = (bid & 7) | ((bid >> 4) << 3);
    const int r0   = rblk * MT;
    const int w    = tid >> 6;
    const int lane = tid & 63;
    const int l4   = lane & 15;
    const int lc   = lane >> 4;
    const int wc   = w & 3;        // col quarter (80 cols)
    const int h    = w >> 2;       // row half (32 rows)

    f32x4 acc[2][5] = {};

    // A staging: thread -> row tid>>3 (0..63), q=tid&7 -> 8 floats (k = q*8..q*8+7)
    const int arow = tid >> 3, akq = tid & 7;
    const float* aptr = hs + (size_t)(r0 + arow) * K + akq * 8;
    const int awoff = (arow * 128 + akq * 16) ^ ((arow & 7) << 4);
    // A frag read: row = h*32 + mt*16 + l4, k = kk*32 + lc*8
    const int a_base = ((h * 32 + l4) * 128 + lc * 16) ^ ((l4 & 7) << 4);  // + mt*2048 + kk*64
    // B: linear double-panel copy; read offsets per (kk,wc,nt,lane)
    const unsigned char* bsrc = img + (size_t)g * 327680 + (size_t)tid * 16;
    const int b_rd = 8192 + wc * 5120 + lane * 16;   // + kk*20480 + nt*1024

    auto packA = [&](float4 x, float4 y) {
        *reinterpret_cast<uint4*>(&smem[awoff]) =
            make_uint4(pk2(x.x, x.y), pk2(x.z, x.w), pk2(y.x, y.y), pk2(y.z, y.w));
    };

    // prologue: A(0) in flight
    float4 ax = *reinterpret_cast<const float4*>(aptr);
    float4 ay = *reinterpret_cast<const float4*>(aptr + 4);

    for (int s = 0; s < NSTEP; ++s) {
        // ---- stage: B double-panel (40KB) via LDS-DMA, A (8KB) convert+write ----
        const unsigned char* bs = bsrc + (size_t)s * 40960;
#pragma unroll
        for (int i = 0; i < 5; ++i)
            __builtin_amdgcn_global_load_lds(
                (const __attribute__((address_space(1))) void*)(bs + i * 8192),
                (__attribute__((address_space(3))) void*)(&smem[8192 + i * 8192 + tid * 16]),
                16, 0, 0);
        packA(ax, ay);                    // auto-waits A(s) only
        __syncthreads();                  // drains B DMA + LDS writes
        // ---- compute; A(s+1) issued first so HBM latency hides under MFMA ----
        if (s + 1 < NSTEP) {
            ax = *reinterpret_cast<const float4*>(aptr + (s + 1) * 64);
            ay = *reinterpret_cast<const float4*>(aptr + (s + 1) * 64 + 4);
        }
        __builtin_amdgcn_s_setprio(1);            // T5: favor MFMA-entering waves
#pragma unroll
        for (int kk = 0; kk < 2; ++kk) {          // t = 2s+kk, same t-order as R12
            short8 av[2];
#pragma unroll
            for (int mt = 0; mt < 2; ++mt)
                av[mt] = *reinterpret_cast<const short8*>(
                    &smem[a_base + mt * 2048 + kk * 64]);
#pragma unroll
            for (int nt = 0; nt < 5; ++nt) {
                short8 bb = *reinterpret_cast<const short8*>(
                    &smem[b_rd + kk * 20480 + nt * 1024]);
                acc[0][nt] = mfma16(av[0], bb, acc[0][nt]);
                acc[1][nt] = mfma16(av[1], bb, acc[1][nt]);
            }
        }
        __builtin_amdgcn_s_setprio(0);
        __syncthreads();                  // buffer reuse guard
    }

    // ---- epilogue: bias + argmax (D: col=l4, row=lc*4+reg within 16x16 tile) ----
    float biasv[5];
#pragma unroll
    for (int nt = 0; nt < 5; ++nt) biasv[nt] = bv[g * V + wc * 80 + nt * 16 + l4];

    float* red_v = reinterpret_cast<float*>(smem);          // [64][4]
    int*   red_i = reinterpret_cast<int*>(smem + 1024);     // [64][4]
    int*   idx_s = reinterpret_cast<int*>(smem + 2048);     // [64]

#pragma unroll
    for (int mt = 0; mt < 2; ++mt) {
#pragma unroll
        for (int reg = 0; reg < 4; ++reg) {
            float bestv = acc[mt][0][reg] + biasv[0];
            int   besti = wc * 80 + l4;
#pragma unroll
            for (int nt = 1; nt < 5; ++nt) {
                float v = acc[mt][nt][reg] + biasv[nt];
                int   ci = wc * 80 + nt * 16 + l4;
                if (v > bestv) { bestv = v; besti = ci; }
            }
#pragma unroll
            for (int m = 1; m < 16; m <<= 1) {
                float ov = __shfl_xor(bestv, m);
                int   oi = __shfl_xor(besti, m);
                if (ov > bestv || (ov == bestv && oi < besti)) { bestv = ov; besti = oi; }
            }
            if (l4 == 0) {
                int row = h * 32 + mt * 16 + lc * 4 + reg;
                red_v[row * 4 + wc] = bestv;
                red_i[row * 4 + wc] = besti;
            }
        }
    }
    __syncthreads();

    int my_bi = -1;
    if (tid < MT) {
        float bb = red_v[tid * 4]; int bi = red_i[tid * 4];
#pragma unroll
        for (int c = 1; c < 4; ++c) {
            float v = red_v[tid * 4 + c]; int ii = red_i[tid * 4 + c];
            if (v > bb || (v == bb && ii < bi)) { bb = v; bi = ii; }
        }
        idx_s[tid] = bi;
        my_bi = bi;
    }
    __syncthreads();

    // ---- gather: 64 rows x 32 float4 = 2048 chunks, 4 per thread ----
#pragma unroll
    for (int i = 0; i < 4; ++i) {
        int idx = i * 512 + tid;
        int row = idx >> 5;
        int d4  = idx & 31;
        int vi  = idx_s[row];
        float4 val = *reinterpret_cast<const float4*>(&cbv[((size_t)(g * V + vi)) * Dg + d4 * 4]);
        *reinterpret_cast<float4*>(&out[((size_t)(r0 + row)) * (G * Dg) + g * Dg + d4 * 4]) = val;
    }
    if (my_bi >= 0) atomicAdd(&hist[g * V + my_bi], 1u);   // last: no post-atomic drain
}

// Perplexity from histogram: one wave.
__global__ void vq_ppl(const unsigned int* __restrict__ hist, float* __restrict__ outp)
{
    int lane = threadIdx.x;  // 64
    float ppl = 0.0f;
    for (int g = 0; g < G; ++g) {
        float local = 0.0f;
        for (int v = lane; v < V; v += 64) {
            float m = (float)hist[g * V + v] * (1.0f / (float)BT);
            local += m * logf(m + 1e-7f);
        }
#pragma unroll
        for (int off = 32; off; off >>= 1) local += __shfl_down(local, off);
        if (lane == 0) ppl += expf(-local);
    }
    if (lane == 0) outp[0] = ppl;
}

extern "C" void kernel_launch(void* const* d_in, const int* in_sizes, int n_in,
                              void* d_out, int out_size, void* d_ws, size_t ws_size,
                              hipStream_t stream)
{
    const float* hs  = (const float*)d_in[0];   // (65536, 512)
    const float* Wm  = (const float*)d_in[1];   // (512, 640)
    const float* bv  = (const float*)d_in[2];   // (640,)
    const float* cbv = (const float*)d_in[3];   // (640, 128)
    float* out = (float*)d_out;                 // 65536*256 floats + 1 float perplexity

    unsigned int*  hist = (unsigned int*)d_ws;
    unsigned char* img  = (unsigned char*)d_ws + WS_IMG;

    hipMemsetAsync(d_ws, 0, G * V * sizeof(unsigned int), stream);
    vq_prep<<<160, 256, 0, stream>>>(Wm, img);
    vq_main<<<2048, 512, 0, stream>>>(hs, img, bv, cbv, out, hist);
    vq_ppl<<<1, 64, 0, stream>>>(hist, out + (size_t)BT * G * Dg);
}

// Round 17
// 91.021 us; speedup vs baseline: 2.1987x; 1.0956x over previous
//
#include <hip/hip_runtime.h>
#include <hip/hip_bf16.h>
#include <hip/hip_fp8.h>

// B=16,S=4096,H=512 ; G=2,V=320,D=256 (Dg=128)
constexpr int BT = 65536;
constexpr int K  = 512;
constexpr int V  = 320;
constexpr int G  = 2;
constexpr int Dg = 128;
constexpr int MT = 64;           // rows per block; 8 waves = 2 row-halves x 4 col-quarters
constexpr int NSTEP = 8;         // K/64 (BK=64 — R12/R16 structure)
constexpr size_t WS_IMG = 4096;  // frag-ordered e4m3 B img (320 KB)

using f32x4 = __attribute__((ext_vector_type(4))) float;

// ---- f32x4 -> 4 OCP e4m3 bytes (logits are pre-scaled by 16 so W' is in range) ----
static __device__ __forceinline__ unsigned cvt4(float a, float b, float c, float d) {
#if __has_builtin(__builtin_amdgcn_cvt_pk_fp8_f32)
    int r = 0;
    r = __builtin_amdgcn_cvt_pk_fp8_f32(a, b, r, false);   // bytes 0-1
    r = __builtin_amdgcn_cvt_pk_fp8_f32(c, d, r, true);    // bytes 2-3
    return (unsigned)r;
#else
    __hip_fp8_e4m3 ha(a), hb(b), hc(c), hd(d);
    return (unsigned)ha.__x | ((unsigned)hb.__x << 8) |
           ((unsigned)hc.__x << 16) | ((unsigned)hd.__x << 24);
#endif
}
static __device__ __forceinline__ f32x4 mfma_fp8(long long a, long long b, f32x4 c) {
    return __builtin_amdgcn_mfma_f32_16x16x32_fp8_fp8(a, b, c, 0, 0, 0);
}

// ---- prep: fragment-ordered e4m3 image of W' = 16*W ----
// chunk id = ((((g*8+s)*2+kk)*4+wc)*5+nt)*64+lane, 8 B each =
// e4m3 of 16*W[s*64+kk*32+(lane>>4)*8+j][g*320+wc*80+nt*16+(lane&15)], j=0..7
__global__ __launch_bounds__(256) void vq_prep(const float* __restrict__ Wm,
                                               unsigned char* __restrict__ img)
{
    int id   = blockIdx.x * 256 + threadIdx.x;   // 0..40959
    int lane = id & 63;
    int r    = id >> 6;
    int nt   = r % 5;  r /= 5;
    int wc   = r & 3;  r >>= 2;
    int kk   = r & 1;  r >>= 1;
    int s    = r & 7;
    int g    = r >> 3;
    int col  = g * V + wc * 80 + nt * 16 + (lane & 15);
    int kb   = s * 64 + kk * 32 + (lane >> 4) * 8;
    float v[8];
#pragma unroll
    for (int j = 0; j < 8; ++j) v[j] = 16.0f * Wm[(size_t)(kb + j) * 640 + col];
    *reinterpret_cast<uint2*>(img + (size_t)id * 8) =
        make_uint2(cvt4(v[0], v[1], v[2], v[3]), cvt4(v[4], v[5], v[6], v[7]));
}

// ---- main: fp8 MFMA GEMM (64x320x512), BK=64, 8 k-steps, 8 waves (R16 structure) ----
// LDS 24KB: A frag-ordered [0,4K): region ((h*2+mt)*2+kk)*512 + lane*8 ;
//           B [4K,24K): kk*10240 + (wc*5+nt)*512 + lane*8 (linear DMA copy).
// grid 2048: g=(bid>>3)&1, rblk=(bid&7)|((bid>>4)<<3) (bid,bid+8 same XCD share hs).
__global__ __launch_bounds__(512) void vq_main(
    const float* __restrict__ hs, const unsigned char* __restrict__ img,
    const float* __restrict__ bv, const float* __restrict__ cbv,
    float* __restrict__ out, unsigned int* __restrict__ hist)
{
    __shared__ __align__(16) unsigned char smem[24576];

    const int tid  = threadIdx.x;
    const int bid  = blockIdx.x;
    const int g    = (bid >> 3) & 1;
    const int rblk = (bid & 7) | ((bid >> 4) << 3);
    const int r0   = rblk * MT;
    const int w    = tid >> 6;
    const int lane = tid & 63;
    const int l4   = lane & 15;
    const int wc   = w & 3;        // col quarter (80 cols)
    const int h    = w >> 2;       // row half (32 rows)
    const int lc   = lane >> 4;
    (void)lc;

    f32x4 acc[2][5] = {};

    // A staging: thread -> row tid>>3 (0..63), kq = tid&7 -> 8 floats (k = kq*8..+7)
    const int arow = tid >> 3, akq = tid & 7;
    const float* aptr = hs + (size_t)(r0 + arow) * K + akq * 8;
    // write slot: region = ((row>>5)*2 + ((row>>4)&1))*2 + (kq>>2); lane' = (row&15) + 16*(kq&3)
    const int awoff = (((arow >> 5) * 2 + ((arow >> 4) & 1)) * 2 + (akq >> 2)) * 512
                      + ((arow & 15) + 16 * (akq & 3)) * 8;
    // A frag read bases: region ((h*2+mt)*2+kk)*512 + lane*8  (contiguous 512B/wave = conflict-free)
    // B: frag-ordered, wave reads its quarter
    const unsigned char* bsrc = img + (size_t)g * 163840 + (size_t)tid * 16;
    const int b_rd = 4096 + wc * 5 * 512 + lane * 8;   // + kk*10240 + nt*512

    auto packA = [&](float4 x, float4 y) {
        *reinterpret_cast<uint2*>(&smem[awoff]) =
            make_uint2(cvt4(x.x, x.y, x.z, x.w), cvt4(y.x, y.y, y.z, y.w));
    };

    // prologue: A(0) in flight
    float4 ax = *reinterpret_cast<const float4*>(aptr);
    float4 ay = *reinterpret_cast<const float4*>(aptr + 4);

    for (int s = 0; s < NSTEP; ++s) {
        // ---- stage: B step-region (20KB) via LDS-DMA, A (4KB) convert+write ----
        const unsigned char* bs = bsrc + (size_t)s * 20480;
#pragma unroll
        for (int i = 0; i < 2; ++i)
            __builtin_amdgcn_global_load_lds(
                (const __attribute__((address_space(1))) void*)(bs + i * 8192),
                (__attribute__((address_space(3))) void*)(&smem[4096 + i * 8192 + tid * 16]),
                16, 0, 0);
        if (tid < 256)
            __builtin_amdgcn_global_load_lds(
                (const __attribute__((address_space(1))) void*)(bs + 16384),
                (__attribute__((address_space(3))) void*)(&smem[4096 + 16384 + tid * 16]),
                16, 0, 0);
        packA(ax, ay);                    // auto-waits A(s) only
        __syncthreads();                  // drains B DMA + LDS writes
        // ---- compute; A(s+1) issued first so HBM latency hides under MFMA ----
        if (s + 1 < NSTEP) {
            ax = *reinterpret_cast<const float4*>(aptr + (s + 1) * 64);
            ay = *reinterpret_cast<const float4*>(aptr + (s + 1) * 64 + 4);
        }
        __builtin_amdgcn_s_setprio(1);            // T5
#pragma unroll
        for (int kk = 0; kk < 2; ++kk) {          // t = 2s+kk
            long long a0 = *reinterpret_cast<const long long*>(
                &smem[((h * 2 + 0) * 2 + kk) * 512 + lane * 8]);
            long long a1 = *reinterpret_cast<const long long*>(
                &smem[((h * 2 + 1) * 2 + kk) * 512 + lane * 8]);
#pragma unroll
            for (int nt = 0; nt < 5; ++nt) {
                long long bb = *reinterpret_cast<const long long*>(
                    &smem[b_rd + kk * 10240 + nt * 512]);
                acc[0][nt] = mfma_fp8(a0, bb, acc[0][nt]);
                acc[1][nt] = mfma_fp8(a1, bb, acc[1][nt]);
            }
        }
        __builtin_amdgcn_s_setprio(0);
        __syncthreads();                  // buffer reuse guard
    }

    // ---- epilogue: bias (x16 to match scaled logits) + argmax ----
    // D layout: col=l4, row=lc*4+reg within 16x16 tile
    float biasv[5];
#pragma unroll
    for (int nt = 0; nt < 5; ++nt) biasv[nt] = 16.0f * bv[g * V + wc * 80 + nt * 16 + l4];

    float* red_v = reinterpret_cast<float*>(smem);          // [64][4]
    int*   red_i = reinterpret_cast<int*>(smem + 1024);     // [64][4]
    int*   idx_s = reinterpret_cast<int*>(smem + 2048);     // [64]

#pragma unroll
    for (int mt = 0; mt < 2; ++mt) {
#pragma unroll
        for (int reg = 0; reg < 4; ++reg) {
            float bestv = acc[mt][0][reg] + biasv[0];
            int   besti = wc * 80 + l4;
#pragma unroll
            for (int nt = 1; nt < 5; ++nt) {
                float v = acc[mt][nt][reg] + biasv[nt];
                int   ci = wc * 80 + nt * 16 + l4;
                if (v > bestv) { bestv = v; besti = ci; }
            }
#pragma unroll
            for (int m = 1; m < 16; m <<= 1) {
                float ov = __shfl_xor(bestv, m);
                int   oi = __shfl_xor(besti, m);
                if (ov > bestv || (ov == bestv && oi < besti)) { bestv = ov; besti = oi; }
            }
            if (l4 == 0) {
                int row = h * 32 + mt * 16 + (lane >> 4) * 4 + reg;
                red_v[row * 4 + wc] = bestv;
                red_i[row * 4 + wc] = besti;
            }
        }
    }
    __syncthreads();

    int my_bi = -1;
    if (tid < MT) {
        float bb = red_v[tid * 4]; int bi = red_i[tid * 4];
#pragma unroll
        for (int c = 1; c < 4; ++c) {
            float v = red_v[tid * 4 + c]; int ii = red_i[tid * 4 + c];
            if (v > bb || (v == bb && ii < bi)) { bb = v; bi = ii; }
        }
        idx_s[tid] = bi;
        my_bi = bi;
    }
    __syncthreads();

    // ---- gather: 64 rows x 32 float4 = 2048 chunks, 4 per thread ----
#pragma unroll
    for (int i = 0; i < 4; ++i) {
        int idx = i * 512 + tid;
        int row = idx >> 5;
        int d4  = idx & 31;
        int vi  = idx_s[row];
        float4 val = *reinterpret_cast<const float4*>(&cbv[((size_t)(g * V + vi)) * Dg + d4 * 4]);
        *reinterpret_cast<float4*>(&out[((size_t)(r0 + row)) * (G * Dg) + g * Dg + d4 * 4]) = val;
    }
    if (my_bi >= 0) atomicAdd(&hist[g * V + my_bi], 1u);   // last: no post-atomic drain
}

// Perplexity from histogram: one wave.
__global__ void vq_ppl(const unsigned int* __restrict__ hist, float* __restrict__ outp)
{
    int lane = threadIdx.x;  // 64
    float ppl = 0.0f;
    for (int g = 0; g < G; ++g) {
        float local = 0.0f;
        for (int v = lane; v < V; v += 64) {
            float m = (float)hist[g * V + v] * (1.0f / (float)BT);
            local += m * logf(m + 1e-7f);
        }
#pragma unroll
        for (int off = 32; off; off >>= 1) local += __shfl_down(local, off);
        if (lane == 0) ppl += expf(-local);
    }
    if (lane == 0) outp[0] = ppl;
}

extern "C" void kernel_launch(void* const* d_in, const int* in_sizes, int n_in,
                              void* d_out, int out_size, void* d_ws, size_t ws_size,
                              hipStream_t stream)
{
    const float* hs  = (const float*)d_in[0];   // (65536, 512)
    const float* Wm  = (const float*)d_in[1];   // (512, 640)
    const float* bv  = (const float*)d_in[2];   // (640,)
    const float* cbv = (const float*)d_in[3];   // (640, 128)
    float* out = (float*)d_out;                 // 65536*256 floats + 1 float perplexity

    unsigned int*  hist = (unsigned int*)d_ws;
    unsigned char* img  = (unsigned char*)d_ws + WS_IMG;

    hipMemsetAsync(d_ws, 0, G * V * sizeof(unsigned int), stream);
    vq_prep<<<160, 256, 0, stream>>>(Wm, img);
    vq_main<<<2048, 512, 0, stream>>>(hs, img, bv, cbv, out, hist);
    vq_ppl<<<1, 64, 0, stream>>>(hist, out + (size_t)BT * G * Dg);
}

// Round 18
// 85.046 us; speedup vs baseline: 2.3531x; 1.0703x over previous
//
#include <hip/hip_runtime.h>
#include <hip/hip_bf16.h>
#include <hip/hip_fp8.h>

// B=16,S=4096,H=512 ; G=2,V=320,D=256 (Dg=128)
constexpr int BT = 65536;
constexpr int K  = 512;
constexpr int V  = 320;
constexpr int G  = 2;
constexpr int Dg = 128;
constexpr int MT = 64;           // rows per block; 8 waves = 2 row-halves x 4 col-quarters
constexpr int NSTEP = 8;         // K/64
constexpr size_t WS_IMG = 4096;  // frag-ordered e4m3 B img (320 KB), kk-paired 16B chunks

using f32x4 = __attribute__((ext_vector_type(4))) float;

static __device__ __forceinline__ unsigned cvt4(float a, float b, float c, float d) {
#if __has_builtin(__builtin_amdgcn_cvt_pk_fp8_f32)
    int r = 0;
    r = __builtin_amdgcn_cvt_pk_fp8_f32(a, b, r, false);   // bytes 0-1
    r = __builtin_amdgcn_cvt_pk_fp8_f32(c, d, r, true);    // bytes 2-3
    return (unsigned)r;
#else
    __hip_fp8_e4m3 ha(a), hb(b), hc(c), hd(d);
    return (unsigned)ha.__x | ((unsigned)hb.__x << 8) |
           ((unsigned)hc.__x << 16) | ((unsigned)hd.__x << 24);
#endif
}
static __device__ __forceinline__ long long mk64(unsigned lo, unsigned hi) {
    return (long long)(((unsigned long long)hi << 32) | lo);
}
static __device__ __forceinline__ f32x4 mfma_fp8(long long a, long long b, f32x4 c) {
    return __builtin_amdgcn_mfma_f32_16x16x32_fp8_fp8(a, b, c, 0, 0, 0);
}

// ---- prep: e4m3 image of W' = 16*W, kk-PAIRED 16B chunks ----
// chunk id = (((g*8+s)*4+wc)*5+nt)*64+lane, 16 B = [kk0: k=s*64+(lane>>4)*8+j]
// [kk1: k=+32], col = g*320+wc*80+nt*16+(lane&15)
__global__ __launch_bounds__(256) void vq_prep(const float* __restrict__ Wm,
                                               unsigned char* __restrict__ img)
{
    int id   = blockIdx.x * 256 + threadIdx.x;   // 0..20479 (grid 80)
    int lane = id & 63;
    int r    = id >> 6;
    int nt   = r % 5;  r /= 5;
    int wc   = r & 3;  r >>= 2;
    int s    = r & 7;
    int g    = r >> 3;
    int col  = g * V + wc * 80 + nt * 16 + (lane & 15);
    int kb   = s * 64 + (lane >> 4) * 8;
    float v0[8], v1[8];
#pragma unroll
    for (int j = 0; j < 8; ++j) {
        v0[j] = 16.0f * Wm[(size_t)(kb + j) * 640 + col];
        v1[j] = 16.0f * Wm[(size_t)(kb + 32 + j) * 640 + col];
    }
    *reinterpret_cast<uint4*>(img + (size_t)id * 16) =
        make_uint4(cvt4(v0[0], v0[1], v0[2], v0[3]), cvt4(v0[4], v0[5], v0[6], v0[7]),
                   cvt4(v1[0], v1[1], v1[2], v1[3]), cvt4(v1[4], v1[5], v1[6], v1[7]));
}

// ---- main: fp8 MFMA GEMM (64x320x512), BK=64, b128 LDS accesses ----
// LDS 24KB: A [0,4K): region (row>>4)*1024 + lane*16 (16B = kk0|kk1 frag pair);
//           B [4K,24K): (wc*5+nt)*1024 + lane*16 (kk-paired chunks, linear DMA).
// grid 2048: g=(bid>>3)&1, rblk=(bid&7)|((bid>>4)<<3).
__global__ __launch_bounds__(512) void vq_main(
    const float* __restrict__ hs, const unsigned char* __restrict__ img,
    const float* __restrict__ bv, const float* __restrict__ cbv,
    float* __restrict__ out, unsigned int* __restrict__ hist)
{
    __shared__ __align__(16) unsigned char smem[24576];

    const int tid  = threadIdx.x;
    const int bid  = blockIdx.x;
    const int g    = (bid >> 3) & 1;
    const int rblk = (bid & 7) | ((bid >> 4) << 3);
    const int r0   = rblk * MT;
    const int w    = tid >> 6;
    const int lane = tid & 63;
    const int l4   = lane & 15;
    const int wc   = w & 3;        // col quarter (80 cols)
    const int h    = w >> 2;       // row half (32 rows)

    f32x4 acc[2][5] = {};

    // A staging: thread -> row tid>>3 (0..63), akq = tid&7 -> 8 floats (k = akq*8..+7)
    // write 8B into the kk-paired slot: region (row>>4)*1024 + lane'*16 + kk*8,
    // lane' = (row&15)+16*(akq&3), kk = akq>>2.
    const int arow = tid >> 3, akq = tid & 7;
    const float* aptr = hs + (size_t)(r0 + arow) * K + akq * 8;
    const int awoff = (arow >> 4) * 1024 + ((arow & 15) + 16 * (akq & 3)) * 16 + (akq >> 2) * 8;
    // A frag read bases (b128, contiguous 1024B/wave = conflict-free)
    const int a_rd0 = (h * 2 + 0) * 1024 + lane * 16;
    const int a_rd1 = (h * 2 + 1) * 1024 + lane * 16;
    // B: DMA linear; read per (wc,nt) contiguous
    const unsigned char* bsrc = img + (size_t)g * 163840 + (size_t)tid * 16;
    const int b_rd = 4096 + wc * 5 * 1024 + lane * 16;   // + nt*1024

    auto packA = [&](float4 x, float4 y) {
        *reinterpret_cast<uint2*>(&smem[awoff]) =
            make_uint2(cvt4(x.x, x.y, x.z, x.w), cvt4(y.x, y.y, y.z, y.w));
    };

    // prologue: A(0) in flight
    float4 ax = *reinterpret_cast<const float4*>(aptr);
    float4 ay = *reinterpret_cast<const float4*>(aptr + 4);

    for (int s = 0; s < NSTEP; ++s) {
        // ---- stage: B step-region (20KB) via LDS-DMA, A (4KB) convert+write ----
        const unsigned char* bs = bsrc + (size_t)s * 20480;
#pragma unroll
        for (int i = 0; i < 2; ++i)
            __builtin_amdgcn_global_load_lds(
                (const __attribute__((address_space(1))) void*)(bs + i * 8192),
                (__attribute__((address_space(3))) void*)(&smem[4096 + i * 8192 + tid * 16]),
                16, 0, 0);
        if (tid < 256)
            __builtin_amdgcn_global_load_lds(
                (const __attribute__((address_space(1))) void*)(bs + 16384),
                (__attribute__((address_space(3))) void*)(&smem[4096 + 16384 + tid * 16]),
                16, 0, 0);
        packA(ax, ay);                    // auto-waits A(s) only
        __syncthreads();                  // drains B DMA + LDS writes
        // ---- compute; A(s+1) issued first so HBM latency hides under MFMA ----
        if (s + 1 < NSTEP) {
            ax = *reinterpret_cast<const float4*>(aptr + (s + 1) * 64);
            ay = *reinterpret_cast<const float4*>(aptr + (s + 1) * 64 + 4);
        }
        __builtin_amdgcn_s_setprio(1);            // T5
        {
            uint4 a0 = *reinterpret_cast<const uint4*>(&smem[a_rd0]);
            uint4 a1 = *reinterpret_cast<const uint4*>(&smem[a_rd1]);
            long long a0k0 = mk64(a0.x, a0.y), a0k1 = mk64(a0.z, a0.w);
            long long a1k0 = mk64(a1.x, a1.y), a1k1 = mk64(a1.z, a1.w);
#pragma unroll
            for (int nt = 0; nt < 5; ++nt) {
                uint4 bb = *reinterpret_cast<const uint4*>(&smem[b_rd + nt * 1024]);
                long long bk0 = mk64(bb.x, bb.y), bk1 = mk64(bb.z, bb.w);
                acc[0][nt] = mfma_fp8(a0k0, bk0, acc[0][nt]);   // kk=0 first,
                acc[0][nt] = mfma_fp8(a0k1, bk1, acc[0][nt]);   // kk=1 second (R17 order)
                acc[1][nt] = mfma_fp8(a1k0, bk0, acc[1][nt]);
                acc[1][nt] = mfma_fp8(a1k1, bk1, acc[1][nt]);
            }
        }
        __builtin_amdgcn_s_setprio(0);
        __syncthreads();                  // buffer reuse guard
    }

    // ---- epilogue: bias (x16 to match scaled logits) + argmax ----
    float biasv[5];
#pragma unroll
    for (int nt = 0; nt < 5; ++nt) biasv[nt] = 16.0f * bv[g * V + wc * 80 + nt * 16 + l4];

    float* red_v = reinterpret_cast<float*>(smem);          // [64][4]
    int*   red_i = reinterpret_cast<int*>(smem + 1024);     // [64][4]
    int*   idx_s = reinterpret_cast<int*>(smem + 2048);     // [64]

#pragma unroll
    for (int mt = 0; mt < 2; ++mt) {
#pragma unroll
        for (int reg = 0; reg < 4; ++reg) {
            float bestv = acc[mt][0][reg] + biasv[0];
            int   besti = wc * 80 + l4;
#pragma unroll
            for (int nt = 1; nt < 5; ++nt) {
                float v = acc[mt][nt][reg] + biasv[nt];
                int   ci = wc * 80 + nt * 16 + l4;
                if (v > bestv) { bestv = v; besti = ci; }
            }
#pragma unroll
            for (int m = 1; m < 16; m <<= 1) {
                float ov = __shfl_xor(bestv, m);
                int   oi = __shfl_xor(besti, m);
                if (ov > bestv || (ov == bestv && oi < besti)) { bestv = ov; besti = oi; }
            }
            if (l4 == 0) {
                int row = h * 32 + mt * 16 + (lane >> 4) * 4 + reg;
                red_v[row * 4 + wc] = bestv;
                red_i[row * 4 + wc] = besti;
            }
        }
    }
    __syncthreads();

    int my_bi = -1;
    if (tid < MT) {
        float bb = red_v[tid * 4]; int bi = red_i[tid * 4];
#pragma unroll
        for (int c = 1; c < 4; ++c) {
            float v = red_v[tid * 4 + c]; int ii = red_i[tid * 4 + c];
            if (v > bb || (v == bb && ii < bi)) { bb = v; bi = ii; }
        }
        idx_s[tid] = bi;
        my_bi = bi;
    }
    __syncthreads();

    // ---- gather: 64 rows x 32 float4 = 2048 chunks, 4 per thread ----
#pragma unroll
    for (int i = 0; i < 4; ++i) {
        int idx = i * 512 + tid;
        int row = idx >> 5;
        int d4  = idx & 31;
        int vi  = idx_s[row];
        float4 val = *reinterpret_cast<const float4*>(&cbv[((size_t)(g * V + vi)) * Dg + d4 * 4]);
        *reinterpret_cast<float4*>(&out[((size_t)(r0 + row)) * (G * Dg) + g * Dg + d4 * 4]) = val;
    }
    if (my_bi >= 0) atomicAdd(&hist[g * V + my_bi], 1u);   // last: no post-atomic drain
}

// Perplexity from histogram: one wave.
__global__ void vq_ppl(const unsigned int* __restrict__ hist, float* __restrict__ outp)
{
    int lane = threadIdx.x;  // 64
    float ppl = 0.0f;
    for (int g = 0; g < G; ++g) {
        float local = 0.0f;
        for (int v = lane; v < V; v += 64) {
            float m = (float)hist[g * V + v] * (1.0f / (float)BT);
            local += m * logf(m + 1e-7f);
        }
#pragma unroll
        for (int off = 32; off; off >>= 1) local += __shfl_down(local, off);
        if (lane == 0) ppl += expf(-local);
    }
    if (lane == 0) outp[0] = ppl;
}

extern "C" void kernel_launch(void* const* d_in, const int* in_sizes, int n_in,
                              void* d_out, int out_size, void* d_ws, size_t ws_size,
                              hipStream_t stream)
{
    const float* hs  = (const float*)d_in[0];   // (65536, 512)
    const float* Wm  = (const float*)d_in[1];   // (512, 640)
    const float* bv  = (const float*)d_in[2];   // (640,)
    const float* cbv = (const float*)d_in[3];   // (640, 128)
    float* out = (float*)d_out;                 // 65536*256 floats + 1 float perplexity

    unsigned int*  hist = (unsigned int*)d_ws;
    unsigned char* img  = (unsigned char*)d_ws + WS_IMG;

    hipMemsetAsync(d_ws, 0, G * V * sizeof(unsigned int), stream);
    vq_prep<<<80, 256, 0, stream>>>(Wm, img);
    vq_main<<<2048, 512, 0, stream>>>(hs, img, bv, cbv, out, hist);
    vq_ppl<<<1, 64, 0, stream>>>(hist, out + (size_t)BT * G * Dg);
}